// Round 1
// baseline (136.917 us; speedup 1.0000x reference)
//
#include <hip/hip_runtime.h>
#include <hip/hip_bf16.h>
#include <stdint.h>

#define NN 8192
#define DD 128

typedef __attribute__((ext_vector_type(8))) short short8;
typedef __attribute__((ext_vector_type(4))) float f32x4;

__device__ __forceinline__ unsigned short f2bf_rne(float x) {
    union { float f; uint32_t u; } v; v.f = x;
    uint32_t r = v.u + 0x7FFFu + ((v.u >> 16) & 1u);
    return (unsigned short)(r >> 16);
}

// Prep: cast ys -> bf16 (RNE) and compute exact fp32 row norms sq[i].
__global__ __launch_bounds__(256) void prep_kernel(const float* __restrict__ ys,
                                                   unsigned short* __restrict__ ybf,
                                                   float* __restrict__ sq) {
    int row = blockIdx.x * 8 + (threadIdx.x >> 5);  // 32 lanes per row
    int c = threadIdx.x & 31;                       // float4 index within row
    float4 v = ((const float4*)(ys + (size_t)row * DD))[c];
    ushort4 o;
    o.x = f2bf_rne(v.x); o.y = f2bf_rne(v.y); o.z = f2bf_rne(v.z); o.w = f2bf_rne(v.w);
    ((ushort4*)(ybf + (size_t)row * DD))[c] = o;
    float s = v.x * v.x + v.y * v.y + v.z * v.z + v.w * v.w;
#pragma unroll
    for (int m = 16; m >= 1; m >>= 1) s += __shfl_xor(s, m);  // reduce within 32-lane row group
    if (c == 0) sq[row] = s;
}

// Main: 128x128 output tile per block, upper-triangular block grid.
// 4 waves (2x2), each wave computes a 64x64 sub-tile via 4x4 fragments of
// mfma_f32_16x16x32_bf16 over K=128 (4 k-steps).
__global__ __launch_bounds__(256) void loss_kernel(const unsigned short* __restrict__ ybf,
                                                   const float* __restrict__ sq,
                                                   const int* __restrict__ lab,
                                                   float* __restrict__ out) {
    int bj = blockIdx.x, bi = blockIdx.y;
    if (bi > bj) return;  // upper triangle of block grid only

    __shared__ __align__(16) unsigned char smA[32768];  // 128 rows x 256B, XOR-swizzled 16B chunks
    __shared__ __align__(16) unsigned char smB[32768];
    __shared__ float sqA[128], sqB[128];
    __shared__ int labA[128], labB[128];

    int t = threadIdx.x;
    int i0 = bi * 128, j0 = bj * 128;

    // Stage tiles. Each row = 128 bf16 = 256B = 16 chunks of 16B.
    // Swizzle: chunk slot = c16 ^ (row & 7)  (T2 st-16x32 style).
#pragma unroll
    for (int k = 0; k < 8; ++k) {
        int idx = k * 256 + t;
        int row = idx >> 4, c16 = idx & 15;
        uint4 va = *(const uint4*)(ybf + (size_t)(i0 + row) * DD + c16 * 8);
        *(uint4*)(smA + row * 256 + ((c16 ^ (row & 7)) << 4)) = va;
        uint4 vb = *(const uint4*)(ybf + (size_t)(j0 + row) * DD + c16 * 8);
        *(uint4*)(smB + row * 256 + ((c16 ^ (row & 7)) << 4)) = vb;
    }
    if (t < 128) { sqA[t] = sq[i0 + t]; labA[t] = lab[i0 + t]; }
    else         { int u = t - 128; sqB[u] = sq[j0 + u]; labB[u] = lab[j0 + u]; }
    __syncthreads();

    int wave = t >> 6, lane = t & 63;
    int wm = wave >> 1, wn = wave & 1;   // 2x2 wave grid
    int lr = lane & 15, lg = lane >> 4;  // lr: frag row/col, lg: k-group (8 bf16 each)

    f32x4 acc[4][4];
#pragma unroll
    for (int m = 0; m < 4; ++m)
#pragma unroll
        for (int n = 0; n < 4; ++n) acc[m][n] = (f32x4){0.f, 0.f, 0.f, 0.f};

#pragma unroll
    for (int ks = 0; ks < 4; ++ks) {
        int c = ks * 4 + lg;  // 16B chunk index within row (k-offset = c*8 bf16)
        short8 af[4], bfr[4];
#pragma unroll
        for (int m = 0; m < 4; ++m) {
            int row = wm * 64 + m * 16 + lr;
            af[m] = *(const short8*)(smA + row * 256 + ((c ^ (row & 7)) << 4));
        }
#pragma unroll
        for (int n = 0; n < 4; ++n) {
            int row = wn * 64 + n * 16 + lr;
            bfr[n] = *(const short8*)(smB + row * 256 + ((c ^ (row & 7)) << 4));
        }
#pragma unroll
        for (int m = 0; m < 4; ++m)
#pragma unroll
            for (int n = 0; n < 4; ++n)
                acc[m][n] = __builtin_amdgcn_mfma_f32_16x16x32_bf16(af[m], bfr[n], acc[m][n], 0, 0, 0);
    }

    // Epilogue: C layout (verified m89): col = lane&15, row = (lane>>4)*4 + reg.
    float lsum = 0.f;
#pragma unroll
    for (int n = 0; n < 4; ++n) {
        int jl = wn * 64 + n * 16 + lr;
        float sqj = sqB[jl];
        int lj = labB[jl];
        int j = j0 + jl;
#pragma unroll
        for (int m = 0; m < 4; ++m) {
#pragma unroll
            for (int q = 0; q < 4; ++q) {
                int il = wm * 64 + m * 16 + lg * 4 + q;
                int i = i0 + il;
                float d2 = fmaxf(sqA[il] + sqj - 2.0f * acc[m][n][q], 0.0f);
                float term;
                if (labA[il] == lj) {
                    term = d2;                    // positive pair: POS_WEIGHT * d2
                } else if (d2 < 1.0f) {           // EPS^2 = 1: neg term nonzero only here
                    float dd = 1.0f - sqrtf(d2);
                    term = dd * dd;
                } else {
                    term = 0.0f;
                }
                if (i < j) lsum += term;
            }
        }
    }

    // Fold the mean reduction into the partial: 2/(N*(N-1)) (exact in fp32).
    lsum *= (2.0f / ((float)NN * (float)(NN - 1)));

#pragma unroll
    for (int off = 32; off >= 1; off >>= 1) lsum += __shfl_down(lsum, off);
    if (lane == 0) atomicAdd(out, lsum);
}

extern "C" void kernel_launch(void* const* d_in, const int* in_sizes, int n_in,
                              void* d_out, int out_size, void* d_ws, size_t ws_size,
                              hipStream_t stream) {
    const float* ys = (const float*)d_in[0];
    const int* lab = (const int*)d_in[1];
    float* out = (float*)d_out;

    unsigned short* ybf = (unsigned short*)d_ws;                       // 8192*128*2B = 2 MB
    float* sq = (float*)((char*)d_ws + (size_t)NN * DD * 2);           // 32 KB

    hipMemsetAsync(d_out, 0, sizeof(float), stream);
    prep_kernel<<<NN / 8, 256, 0, stream>>>(ys, ybf, sq);
    dim3 grid(64, 64);  // (bj, bi); lower-triangle blocks early-exit
    loss_kernel<<<grid, 256, 0, stream>>>(ybf, sq, lab, out);
}

// Round 2
// 34.524 us; speedup vs baseline: 3.9658x; 3.9658x over previous
//
#include <hip/hip_runtime.h>
#include <hip/hip_bf16.h>
#include <stdint.h>
#include <math.h>

#define NN 8192
#define DD 128
#define NB 64                    // 8192 / 128 tiles per dim
#define NBLK (NB * (NB + 1) / 2) // 2080 upper-triangular blocks

typedef __attribute__((ext_vector_type(8))) short short8;
typedef __attribute__((ext_vector_type(4))) float f32x4;

__device__ __forceinline__ unsigned short f2bf_rne(float x) {
    union { float f; uint32_t u; } v; v.f = x;
    uint32_t r = v.u + 0x7FFFu + ((v.u >> 16) & 1u);
    return (unsigned short)(r >> 16);
}

// Prep: cast ys -> bf16 (RNE) and compute exact fp32 row norms sq[i].
__global__ __launch_bounds__(256) void prep_kernel(const float* __restrict__ ys,
                                                   unsigned short* __restrict__ ybf,
                                                   float* __restrict__ sq) {
    int row = blockIdx.x * 8 + (threadIdx.x >> 5);
    int c = threadIdx.x & 31;
    float4 v = ((const float4*)(ys + (size_t)row * DD))[c];
    ushort4 o;
    o.x = f2bf_rne(v.x); o.y = f2bf_rne(v.y); o.z = f2bf_rne(v.z); o.w = f2bf_rne(v.w);
    ((ushort4*)(ybf + (size_t)row * DD))[c] = o;
    float s = v.x * v.x + v.y * v.y + v.z * v.z + v.w * v.w;
#pragma unroll
    for (int m = 16; m >= 1; m >>= 1) s += __shfl_xor(s, m);
    if (c == 0) sq[row] = s;
}

// 128x128 tile per block; 4 waves (2x2) x 64x64 wave-tiles; K split into two
// 64-wide halves staged in 16KB LDS tiles (total LDS ~35KB -> 4 blocks/CU).
// No global atomics: one partial per block written to d_ws.
__global__ __launch_bounds__(256, 4) void loss_kernel(const unsigned short* __restrict__ ybf,
                                                      const float* __restrict__ sq,
                                                      const int* __restrict__ lab,
                                                      float* __restrict__ partial) {
    // Triangular decode: block p -> (bi, bj) with bi <= bj.
    int p = blockIdx.x;
    int q = (NBLK - 1) - p;
    int r = (int)((sqrtf(8.0f * (float)q + 1.0f) - 1.0f) * 0.5f);
    while (r * (r + 1) / 2 > q) --r;
    while ((r + 1) * (r + 2) / 2 <= q) ++r;
    int bi = (NB - 1) - r;
    int bj = (NB - 1) - (q - r * (r + 1) / 2);

    __shared__ __align__(16) unsigned char smA[16384];  // 128 rows x 128B (K-half), XOR-swizzled 16B chunks
    __shared__ __align__(16) unsigned char smB[16384];
    __shared__ float sqA[128], sqB[128];
    __shared__ int labA[128], labB[128];
    __shared__ float wsum[4];

    int t = threadIdx.x;
    int i0 = bi * 128, j0 = bj * 128;

    if (t < 128) { sqA[t] = sq[i0 + t]; labA[t] = lab[i0 + t]; }
    else         { int u = t - 128; sqB[u] = sq[j0 + u]; labB[u] = lab[j0 + u]; }

    int wave = t >> 6, lane = t & 63;
    int wm = wave >> 1, wn = wave & 1;
    int lr = lane & 15, lg = lane >> 4;

    f32x4 acc[4][4];
#pragma unroll
    for (int m = 0; m < 4; ++m)
#pragma unroll
        for (int n = 0; n < 4; ++n) acc[m][n] = (f32x4){0.f, 0.f, 0.f, 0.f};

#pragma unroll
    for (int h = 0; h < 2; ++h) {
        // Stage K-half h: each row contributes 64 bf16 = 128B = 8 x 16B chunks.
#pragma unroll
        for (int k = 0; k < 4; ++k) {
            int idx = k * 256 + t;
            int row = idx >> 3, c8 = idx & 7;
            uint4 va = *(const uint4*)(ybf + (size_t)(i0 + row) * DD + h * 64 + c8 * 8);
            uint4 vb = *(const uint4*)(ybf + (size_t)(j0 + row) * DD + h * 64 + c8 * 8);
            *(uint4*)(smA + row * 128 + ((c8 ^ (row & 7)) << 4)) = va;
            *(uint4*)(smB + row * 128 + ((c8 ^ (row & 7)) << 4)) = vb;
        }
        __syncthreads();
#pragma unroll
        for (int ks = 0; ks < 2; ++ks) {
            int c = ks * 4 + lg;  // 16B chunk within this K-half's 8-chunk row
            short8 af[4], bfr[4];
#pragma unroll
            for (int m = 0; m < 4; ++m) {
                int row = wm * 64 + m * 16 + lr;
                af[m] = *(const short8*)(smA + row * 128 + ((c ^ (row & 7)) << 4));
            }
#pragma unroll
            for (int n = 0; n < 4; ++n) {
                int row = wn * 64 + n * 16 + lr;
                bfr[n] = *(const short8*)(smB + row * 128 + ((c ^ (row & 7)) << 4));
            }
#pragma unroll
            for (int m = 0; m < 4; ++m)
#pragma unroll
                for (int n = 0; n < 4; ++n)
                    acc[m][n] = __builtin_amdgcn_mfma_f32_16x16x32_bf16(af[m], bfr[n], acc[m][n], 0, 0, 0);
        }
        __syncthreads();  // protect LDS before restaging next half
    }

    // Epilogue: C layout col = lane&15, row = (lane>>4)*4 + reg.
    float lsum = 0.f;
#pragma unroll
    for (int n = 0; n < 4; ++n) {
        int jl = wn * 64 + n * 16 + lr;
        float sqj = sqB[jl];
        int lj = labB[jl];
        int j = j0 + jl;
#pragma unroll
        for (int m = 0; m < 4; ++m) {
#pragma unroll
            for (int q2 = 0; q2 < 4; ++q2) {
                int il = wm * 64 + m * 16 + lg * 4 + q2;
                int i = i0 + il;
                float d2 = fmaxf(sqA[il] + sqj - 2.0f * acc[m][n][q2], 0.0f);
                float term;
                if (labA[il] == lj) {
                    term = d2;                 // positive pair
                } else if (d2 < 1.0f) {        // EPS^2 = 1
                    float dd = 1.0f - sqrtf(d2);
                    term = dd * dd;
                } else {
                    term = 0.0f;
                }
                if (i < j) lsum += term;
            }
        }
    }

    lsum *= (2.0f / ((float)NN * (float)(NN - 1)));

#pragma unroll
    for (int off = 32; off >= 1; off >>= 1) lsum += __shfl_down(lsum, off);
    if (lane == 0) wsum[wave] = lsum;
    __syncthreads();
    if (t == 0) partial[p] = wsum[0] + wsum[1] + wsum[2] + wsum[3];
}

__global__ __launch_bounds__(256) void reduce_kernel(const float* __restrict__ partial,
                                                     float* __restrict__ out) {
    int t = threadIdx.x;
    float s = 0.f;
    for (int p = t; p < NBLK; p += 256) s += partial[p];
#pragma unroll
    for (int off = 32; off >= 1; off >>= 1) s += __shfl_down(s, off);
    __shared__ float ws[4];
    if ((t & 63) == 0) ws[t >> 6] = s;
    __syncthreads();
    if (t == 0) out[0] = ws[0] + ws[1] + ws[2] + ws[3];
}

extern "C" void kernel_launch(void* const* d_in, const int* in_sizes, int n_in,
                              void* d_out, int out_size, void* d_ws, size_t ws_size,
                              hipStream_t stream) {
    const float* ys = (const float*)d_in[0];
    const int* lab = (const int*)d_in[1];
    float* out = (float*)d_out;

    unsigned short* ybf = (unsigned short*)d_ws;                          // 2 MB
    float* sq = (float*)((char*)d_ws + (size_t)NN * DD * 2);              // 32 KB
    float* partial = (float*)((char*)d_ws + (size_t)NN * DD * 2 + NN * 4); // 8.3 KB

    prep_kernel<<<NN / 8, 256, 0, stream>>>(ys, ybf, sq);
    loss_kernel<<<NBLK, 256, 0, stream>>>(ybf, sq, lab, partial);
    reduce_kernel<<<1, 256, 0, stream>>>(partial, out);
}